// Round 1
// baseline (3742.677 us; speedup 1.0000x reference)
//
#include <hip/hip_runtime.h>
#include <hip/hip_bf16.h>
#include <math.h>

// ---------------------------------------------------------------------------
// GCN 2-layer forward:
//   support1 = x @ W1                       [100000,512]@[512,256]
//   agg1     = scatter_add(ew * support1[src] -> dst)
//   h        = relu(agg1 + b1)              (fused into gemm2 A-load)
//   support2 = h @ W2                       [100000,256]@[256,40]
//   agg2     = scatter_add(ew * support2[src] -> dst)
//   out      = log_softmax(agg2 + b2)       (fused)
// ---------------------------------------------------------------------------

#define NFEAT 512
#define NHID  256
#define NCLASS 40

// ------------------------- GEMM1: fp32 tiled ------------------------------
// C[M,256] = A[M,512] @ B[512,256].  BM=BN=64, BK=16, 256 thr, 4x4 per thread.
__global__ __launch_bounds__(256) void gemm1_kernel(
    const float* __restrict__ A, const float* __restrict__ B,
    float* __restrict__ C, int M) {
  const int K = NFEAT, N = NHID;
  __shared__ float As[16][64];   // transposed: As[k][m]
  __shared__ float Bs[16][64];
  int tid = threadIdx.x;
  int bm = blockIdx.y * 64;
  int bn = blockIdx.x * 64;
  int tx = tid % 16, ty = tid / 16;      // tx: n-group, ty: m-group
  int arow = tid / 4, akq = tid % 4;     // A tile load mapping (float4)
  int brow = tid / 16, bnq = tid % 16;   // B tile load mapping (float4)
  float acc[4][4] = {};

  for (int k0 = 0; k0 < K; k0 += 16) {
    float4 av = {0.f, 0.f, 0.f, 0.f};
    int gr = bm + arow;
    if (gr < M) av = *(const float4*)(A + (size_t)gr * K + k0 + akq * 4);
    As[akq * 4 + 0][arow] = av.x;
    As[akq * 4 + 1][arow] = av.y;
    As[akq * 4 + 2][arow] = av.z;
    As[akq * 4 + 3][arow] = av.w;
    float4 bv = *(const float4*)(B + (size_t)(k0 + brow) * N + bn + bnq * 4);
    *(float4*)&Bs[brow][bnq * 4] = bv;
    __syncthreads();
#pragma unroll
    for (int k = 0; k < 16; ++k) {
      float4 rav = *(const float4*)&As[k][ty * 4];
      float4 rbv = *(const float4*)&Bs[k][tx * 4];
      float ra[4] = {rav.x, rav.y, rav.z, rav.w};
      float rb[4] = {rbv.x, rbv.y, rbv.z, rbv.w};
#pragma unroll
      for (int i = 0; i < 4; ++i)
#pragma unroll
        for (int j = 0; j < 4; ++j) acc[i][j] += ra[i] * rb[j];
    }
    __syncthreads();
  }
#pragma unroll
  for (int i = 0; i < 4; ++i) {
    int gr = bm + ty * 4 + i;
    if (gr < M) {
      float4 o = {acc[i][0], acc[i][1], acc[i][2], acc[i][3]};
      *(float4*)(C + (size_t)gr * N + bn + tx * 4) = o;
    }
  }
}

// ------------------------- SpMM1: 256-feat scatter-add --------------------
#define EPB1 8
__global__ __launch_bounds__(256) void spmm1_kernel(
    const float* __restrict__ S, const int* __restrict__ src,
    const int* __restrict__ dst, const float* __restrict__ w,
    float* __restrict__ agg, int E) {
  int f = threadIdx.x;
  int e0 = blockIdx.x * EPB1;
#pragma unroll
  for (int i = 0; i < EPB1; ++i) {
    int e = e0 + i;
    if (e >= E) break;
    int s = src[e], d = dst[e];
    float wt = w[e];
    float v = wt * S[(size_t)s * NHID + f];
    atomicAdd(&agg[(size_t)d * NHID + f], v);
  }
}

// ------------------- GEMM2: fused relu(agg1+b1) @ W2 ----------------------
// One thread per row; W2 (256x40) + b1 staged in LDS.
__global__ __launch_bounds__(256) void gemm2_kernel(
    const float* __restrict__ H, const float* __restrict__ W2,
    const float* __restrict__ b1, float* __restrict__ S2, int M) {
  __shared__ float W2s[NHID * NCLASS];
  __shared__ float b1s[NHID];
  for (int i = threadIdx.x; i < NHID * NCLASS; i += 256) W2s[i] = W2[i];
  if (threadIdx.x < NHID) b1s[threadIdx.x] = b1[threadIdx.x];
  __syncthreads();
  int row = blockIdx.x * 256 + threadIdx.x;
  if (row >= M) return;
  const float4* W2v = (const float4*)W2s;  // row k: 10 float4 at k*10
  float4 acc[10];
#pragma unroll
  for (int j = 0; j < 10; ++j) acc[j] = make_float4(0.f, 0.f, 0.f, 0.f);
  const float* hrow = H + (size_t)row * NHID;
  for (int k = 0; k < NHID; k += 4) {
    float4 hv = *(const float4*)(hrow + k);
    float a[4] = {fmaxf(hv.x + b1s[k + 0], 0.f), fmaxf(hv.y + b1s[k + 1], 0.f),
                  fmaxf(hv.z + b1s[k + 2], 0.f), fmaxf(hv.w + b1s[k + 3], 0.f)};
#pragma unroll
    for (int kk = 0; kk < 4; ++kk) {
#pragma unroll
      for (int j = 0; j < 10; ++j) {
        float4 wv = W2v[(k + kk) * 10 + j];
        acc[j].x += a[kk] * wv.x;
        acc[j].y += a[kk] * wv.y;
        acc[j].z += a[kk] * wv.z;
        acc[j].w += a[kk] * wv.w;
      }
    }
  }
  float4* out = (float4*)(S2 + (size_t)row * NCLASS);
#pragma unroll
  for (int j = 0; j < 10; ++j) out[j] = acc[j];
}

// ------------------------- SpMM2: 40-feat scatter-add ---------------------
__global__ __launch_bounds__(320) void spmm2_kernel(
    const float* __restrict__ S, const int* __restrict__ src,
    const int* __restrict__ dst, const float* __restrict__ w,
    float* __restrict__ agg, int E) {
  int el = threadIdx.x / NCLASS;
  int f = threadIdx.x % NCLASS;
  int e = blockIdx.x * 8 + el;
  if (e >= E) return;
  int s = src[e], d = dst[e];
  float v = w[e] * S[(size_t)s * NCLASS + f];
  atomicAdd(&agg[(size_t)d * NCLASS + f], v);
}

// ------------------- fused bias + log_softmax (wave/row) ------------------
__global__ __launch_bounds__(256) void lsm_kernel(
    const float* __restrict__ agg, const float* __restrict__ b2,
    float* __restrict__ out, int M) {
  int wid = (blockIdx.x * 256 + threadIdx.x) / 64;
  int lane = threadIdx.x & 63;
  if (wid >= M) return;
  float v = -INFINITY;
  if (lane < NCLASS) v = agg[(size_t)wid * NCLASS + lane] + b2[lane];
  float m = v;
#pragma unroll
  for (int off = 32; off; off >>= 1) m = fmaxf(m, __shfl_xor(m, off));
  float ex = (lane < NCLASS) ? __expf(v - m) : 0.f;
  float s = ex;
#pragma unroll
  for (int off = 32; off; off >>= 1) s += __shfl_xor(s, off);
  float lse = m + __logf(s);
  if (lane < NCLASS) out[(size_t)wid * NCLASS + lane] = v - lse;
}

// ---------------------------------------------------------------------------
extern "C" void kernel_launch(void* const* d_in, const int* in_sizes, int n_in,
                              void* d_out, int out_size, void* d_ws,
                              size_t ws_size, hipStream_t stream) {
  const float* x    = (const float*)d_in[0];
  const int* esrc   = (const int*)d_in[1];
  const int* edst   = (const int*)d_in[2];
  const float* ew   = (const float*)d_in[3];
  const float* W1   = (const float*)d_in[4];
  const float* b1   = (const float*)d_in[5];
  const float* W2   = (const float*)d_in[6];
  const float* b2   = (const float*)d_in[7];
  float* out = (float*)d_out;

  const int M = in_sizes[0] / NFEAT;   // 100000
  const int E = in_sizes[1];           // 3200000

  float* support1 = (float*)d_ws;                       // M*256 f32
  float* agg1     = support1 + (size_t)M * NHID;        // M*256 f32
  float* support2 = agg1 + (size_t)M * NHID;            // M*40 f32
  float* agg2     = support2 + (size_t)M * NCLASS;      // M*40 f32

  hipMemsetAsync(agg1, 0, (size_t)M * NHID * sizeof(float), stream);
  hipMemsetAsync(agg2, 0, (size_t)M * NCLASS * sizeof(float), stream);

  // GEMM1: support1 = x @ W1
  dim3 g1(NHID / 64, (M + 63) / 64);
  gemm1_kernel<<<g1, 256, 0, stream>>>(x, W1, support1, M);

  // SpMM1: agg1 = scatter_add(ew * support1[src])
  spmm1_kernel<<<(E + EPB1 - 1) / EPB1, 256, 0, stream>>>(support1, esrc, edst,
                                                          ew, agg1, E);

  // GEMM2: support2 = relu(agg1 + b1) @ W2
  gemm2_kernel<<<(M + 255) / 256, 256, 0, stream>>>(agg1, W2, b1, support2, M);

  // SpMM2: agg2 = scatter_add(ew * support2[src])
  spmm2_kernel<<<(E + 7) / 8, 320, 0, stream>>>(support2, esrc, edst, ew, agg2,
                                                E);

  // out = log_softmax(agg2 + b2)
  lsm_kernel<<<(M * 64 + 255) / 256, 256, 0, stream>>>(agg2, b2, out, M);
}

// Round 2
// 1581.023 us; speedup vs baseline: 2.3673x; 2.3673x over previous
//
#include <hip/hip_runtime.h>
#include <hip/hip_bf16.h>
#include <math.h>

// ---------------------------------------------------------------------------
// GCN 2-layer forward, CSR-based aggregation (no float atomics):
//   support1 = x @ W1
//   CSR build: deg histogram -> scan -> scatter (per-call, on device)
//   h        = relu(CSR-aggregate(support1) + b1)   [fused epilogue]
//   support2 = h @ W2
//   out      = log_softmax(CSR-aggregate(support2) + b2)  [fully fused]
// ---------------------------------------------------------------------------

#define NFEAT 512
#define NHID  256
#define NCLASS 40

// ------------------------- GEMM1: fp32 tiled ------------------------------
__global__ __launch_bounds__(256) void gemm1_kernel(
    const float* __restrict__ A, const float* __restrict__ B,
    float* __restrict__ C, int M) {
  const int K = NFEAT, N = NHID;
  __shared__ float As[16][64];
  __shared__ float Bs[16][64];
  int tid = threadIdx.x;
  int bm = blockIdx.y * 64;
  int bn = blockIdx.x * 64;
  int tx = tid % 16, ty = tid / 16;
  int arow = tid / 4, akq = tid % 4;
  int brow = tid / 16, bnq = tid % 16;
  float acc[4][4] = {};

  for (int k0 = 0; k0 < K; k0 += 16) {
    float4 av = {0.f, 0.f, 0.f, 0.f};
    int gr = bm + arow;
    if (gr < M) av = *(const float4*)(A + (size_t)gr * K + k0 + akq * 4);
    As[akq * 4 + 0][arow] = av.x;
    As[akq * 4 + 1][arow] = av.y;
    As[akq * 4 + 2][arow] = av.z;
    As[akq * 4 + 3][arow] = av.w;
    float4 bv = *(const float4*)(B + (size_t)(k0 + brow) * N + bn + bnq * 4);
    *(float4*)&Bs[brow][bnq * 4] = bv;
    __syncthreads();
#pragma unroll
    for (int k = 0; k < 16; ++k) {
      float4 rav = *(const float4*)&As[k][ty * 4];
      float4 rbv = *(const float4*)&Bs[k][tx * 4];
      float ra[4] = {rav.x, rav.y, rav.z, rav.w};
      float rb[4] = {rbv.x, rbv.y, rbv.z, rbv.w};
#pragma unroll
      for (int i = 0; i < 4; ++i)
#pragma unroll
        for (int j = 0; j < 4; ++j) acc[i][j] += ra[i] * rb[j];
    }
    __syncthreads();
  }
#pragma unroll
  for (int i = 0; i < 4; ++i) {
    int gr = bm + ty * 4 + i;
    if (gr < M) {
      float4 o = {acc[i][0], acc[i][1], acc[i][2], acc[i][3]};
      *(float4*)(C + (size_t)gr * N + bn + tx * 4) = o;
    }
  }
}

// ------------------------- CSR build --------------------------------------
__global__ __launch_bounds__(256) void hist_kernel(const int* __restrict__ dst,
                                                   int* __restrict__ deg, int E) {
  int e = blockIdx.x * 256 + threadIdx.x;
  if (e < E) atomicAdd(&deg[dst[e]], 1);
}

// per-block inclusive scan (256 elems/block)
__global__ __launch_bounds__(256) void scan1_kernel(const int* __restrict__ deg,
                                                    int* __restrict__ part,
                                                    int* __restrict__ bsums, int M) {
  __shared__ int tmp[256];
  int t = threadIdx.x;
  int i = blockIdx.x * 256 + t;
  int v = (i < M) ? deg[i] : 0;
  tmp[t] = v;
  __syncthreads();
  for (int off = 1; off < 256; off <<= 1) {
    int add = (t >= off) ? tmp[t - off] : 0;
    __syncthreads();
    tmp[t] += add;
    __syncthreads();
  }
  if (i < M) part[i] = tmp[t];
  if (t == 255) bsums[blockIdx.x] = tmp[255];
}

// single-block scan of block sums (nb <= 512)
__global__ __launch_bounds__(512) void scan2_kernel(int* __restrict__ bsums, int nb) {
  __shared__ int tmp[512];
  int t = threadIdx.x;
  int v = (t < nb) ? bsums[t] : 0;
  tmp[t] = v;
  __syncthreads();
  for (int off = 1; off < 512; off <<= 1) {
    int add = (t >= off) ? tmp[t - off] : 0;
    __syncthreads();
    tmp[t] += add;
    __syncthreads();
  }
  if (t < nb) bsums[t] = tmp[t];
}

// rowptr[i] = exclusive prefix = inclusive - deg; also init cursor
__global__ __launch_bounds__(256) void scan3_kernel(
    const int* __restrict__ part, const int* __restrict__ bsums,
    const int* __restrict__ deg, int* __restrict__ rowptr,
    int* __restrict__ cursor, int M) {
  int i = blockIdx.x * 256 + threadIdx.x;
  if (i >= M) return;
  int incl = part[i] + (blockIdx.x > 0 ? bsums[blockIdx.x - 1] : 0);
  int start = incl - deg[i];
  rowptr[i] = start;
  cursor[i] = start;
}

__global__ __launch_bounds__(256) void scatter_kernel(
    const int* __restrict__ src, const int* __restrict__ dst,
    const float* __restrict__ w, int* __restrict__ cursor,
    int* __restrict__ ssrc, float* __restrict__ sw, int E) {
  int e = blockIdx.x * 256 + threadIdx.x;
  if (e >= E) return;
  int d = dst[e];
  int pos = atomicAdd(&cursor[d], 1);
  ssrc[pos] = src[e];
  sw[pos] = w[e];
}

// ---------------- SpMM1 (CSR): one block per dst node ---------------------
// h[node][f] = relu(sum_j w_j * S[src_j][f] + b1[f])
__global__ __launch_bounds__(256) void spmm1_csr_kernel(
    const float* __restrict__ S, const int* __restrict__ rowptr,
    const int* __restrict__ deg, const int* __restrict__ ssrc,
    const float* __restrict__ sw, const float* __restrict__ b1,
    float* __restrict__ h, int M) {
  int node = blockIdx.x;
  int f = threadIdx.x;
  int beg = rowptr[node];
  int n = deg[node];
  __shared__ int s_src[64];
  __shared__ float s_w[64];
  float acc = 0.f;
  for (int j0 = 0; j0 < n; j0 += 64) {
    int cnt = min(64, n - j0);
    if (threadIdx.x < cnt) {
      s_src[threadIdx.x] = ssrc[beg + j0 + threadIdx.x];
      s_w[threadIdx.x] = sw[beg + j0 + threadIdx.x];
    }
    __syncthreads();
    int j = 0;
    for (; j + 4 <= cnt; j += 4) {
      float v0 = S[(size_t)s_src[j + 0] * NHID + f];
      float v1 = S[(size_t)s_src[j + 1] * NHID + f];
      float v2 = S[(size_t)s_src[j + 2] * NHID + f];
      float v3 = S[(size_t)s_src[j + 3] * NHID + f];
      acc += s_w[j + 0] * v0;
      acc += s_w[j + 1] * v1;
      acc += s_w[j + 2] * v2;
      acc += s_w[j + 3] * v3;
    }
    for (; j < cnt; ++j) acc += s_w[j] * S[(size_t)s_src[j] * NHID + f];
    __syncthreads();
  }
  h[(size_t)node * NHID + f] = fmaxf(acc + b1[f], 0.f);
}

// ------------------- GEMM2: h @ W2 (h already relu+bias) ------------------
__global__ __launch_bounds__(256) void gemm2_kernel(
    const float* __restrict__ H, const float* __restrict__ W2,
    float* __restrict__ S2, int M) {
  __shared__ float W2s[NHID * NCLASS];
  for (int i = threadIdx.x; i < NHID * NCLASS; i += 256) W2s[i] = W2[i];
  __syncthreads();
  int row = blockIdx.x * 256 + threadIdx.x;
  if (row >= M) return;
  const float4* W2v = (const float4*)W2s;
  float4 acc[10];
#pragma unroll
  for (int j = 0; j < 10; ++j) acc[j] = make_float4(0.f, 0.f, 0.f, 0.f);
  const float* hrow = H + (size_t)row * NHID;
  for (int k = 0; k < NHID; k += 4) {
    float4 hv = *(const float4*)(hrow + k);
    float a[4] = {hv.x, hv.y, hv.z, hv.w};
#pragma unroll
    for (int kk = 0; kk < 4; ++kk) {
#pragma unroll
      for (int j = 0; j < 10; ++j) {
        float4 wv = W2v[(k + kk) * 10 + j];
        acc[j].x += a[kk] * wv.x;
        acc[j].y += a[kk] * wv.y;
        acc[j].z += a[kk] * wv.z;
        acc[j].w += a[kk] * wv.w;
      }
    }
  }
  float4* out = (float4*)(S2 + (size_t)row * NCLASS);
#pragma unroll
  for (int j = 0; j < 10; ++j) out[j] = acc[j];
}

// -------- SpMM2 (CSR) + bias + log_softmax, one wave per dst node ---------
__global__ __launch_bounds__(256) void spmm2_csr_kernel(
    const float* __restrict__ S2, const int* __restrict__ rowptr,
    const int* __restrict__ deg, const int* __restrict__ ssrc,
    const float* __restrict__ sw, const float* __restrict__ b2,
    float* __restrict__ out, int M) {
  int wid = (blockIdx.x * 256 + threadIdx.x) >> 6;
  int lane = threadIdx.x & 63;
  if (wid >= M) return;
  int beg = rowptr[wid];
  int n = deg[wid];
  float acc = 0.f;
  for (int j0 = 0; j0 < n; j0 += 64) {
    int cnt = min(64, n - j0);
    int msrc = 0;
    float mw = 0.f;
    if (lane < cnt) {
      msrc = ssrc[beg + j0 + lane];
      mw = sw[beg + j0 + lane];
    }
    for (int j = 0; j < cnt; ++j) {
      int s = __shfl(msrc, j);
      float wt = __shfl(mw, j);
      if (lane < NCLASS) acc += wt * S2[(size_t)s * NCLASS + lane];
    }
  }
  float v = (lane < NCLASS) ? acc + b2[lane] : -INFINITY;
  float m = v;
#pragma unroll
  for (int off = 32; off; off >>= 1) m = fmaxf(m, __shfl_xor(m, off));
  float ex = (lane < NCLASS) ? __expf(v - m) : 0.f;
  float s = ex;
#pragma unroll
  for (int off = 32; off; off >>= 1) s += __shfl_xor(s, off);
  float lse = m + __logf(s);
  if (lane < NCLASS) out[(size_t)wid * NCLASS + lane] = v - lse;
}

// ---------------------------------------------------------------------------
extern "C" void kernel_launch(void* const* d_in, const int* in_sizes, int n_in,
                              void* d_out, int out_size, void* d_ws,
                              size_t ws_size, hipStream_t stream) {
  const float* x  = (const float*)d_in[0];
  const int* esrc = (const int*)d_in[1];
  const int* edst = (const int*)d_in[2];
  const float* ew = (const float*)d_in[3];
  const float* W1 = (const float*)d_in[4];
  const float* b1 = (const float*)d_in[5];
  const float* W2 = (const float*)d_in[6];
  const float* b2 = (const float*)d_in[7];
  float* out = (float*)d_out;

  const int M = in_sizes[0] / NFEAT;  // 100000
  const int E = in_sizes[1];          // 3200000

  // workspace layout (~232 MB)
  float* support1 = (float*)d_ws;                     // M*256  (reused as support2)
  float* h        = support1 + (size_t)M * NHID;      // M*256
  int*   deg      = (int*)(h + (size_t)M * NHID);     // M
  int*   part     = deg + M;                          // M
  int*   rowptr   = part + M;                         // M
  int*   cursor   = rowptr + M;                       // M
  int*   bsums    = cursor + M;                       // 512
  int*   ssrc     = bsums + 512;                      // E
  float* sw       = (float*)(ssrc + E);               // E
  float* support2 = support1;                         // alias (support1 dead by then)

  const int nbScan = (M + 255) / 256;  // 391 <= 512

  // ---- CSR build ----
  hipMemsetAsync(deg, 0, (size_t)M * sizeof(int), stream);
  hist_kernel<<<(E + 255) / 256, 256, 0, stream>>>(edst, deg, E);
  scan1_kernel<<<nbScan, 256, 0, stream>>>(deg, part, bsums, M);
  scan2_kernel<<<1, 512, 0, stream>>>(bsums, nbScan);
  scan3_kernel<<<nbScan, 256, 0, stream>>>(part, bsums, deg, rowptr, cursor, M);
  scatter_kernel<<<(E + 255) / 256, 256, 0, stream>>>(esrc, edst, ew, cursor,
                                                      ssrc, sw, E);

  // ---- layer 1 ----
  dim3 g1(NHID / 64, (M + 63) / 64);
  gemm1_kernel<<<g1, 256, 0, stream>>>(x, W1, support1, M);
  spmm1_csr_kernel<<<M, 256, 0, stream>>>(support1, rowptr, deg, ssrc, sw, b1,
                                          h, M);

  // ---- layer 2 (gemm2 output aliases support1; spmm1 done by then) ----
  gemm2_kernel<<<(M + 255) / 256, 256, 0, stream>>>(h, W2, support2, M);
  spmm2_csr_kernel<<<(M * 64 + 255) / 256, 256, 0, stream>>>(
      support2, rowptr, deg, ssrc, sw, b2, out, M);
}

// Round 3
// 1249.509 us; speedup vs baseline: 2.9953x; 1.2653x over previous
//
#include <hip/hip_runtime.h>
#include <hip/hip_bf16.h>
#include <math.h>

// ---------------------------------------------------------------------------
// GCN 2-layer forward, CSR aggregation + bf16 MFMA GEMM1 + bf16 activations.
//   W1t      = transpose(W1) as bf16 [256][512]
//   support1 = x @ W1            (MFMA bf16, out bf16)
//   h        = relu(agg(support1) + b1)   bf16
//   support2 = h @ W2            (per-row fp32, W2 in LDS)
//   out      = log_softmax(agg(support2) + b2)
// ---------------------------------------------------------------------------

#define NFEAT 512
#define NHID  256
#define NCLASS 40

typedef __attribute__((ext_vector_type(4))) float f32x4;
typedef __attribute__((ext_vector_type(8))) short s16x8;

__device__ __forceinline__ ushort f2bf(float f) {
  unsigned u = __float_as_uint(f);
  u = (u + 0x7fffu + ((u >> 16) & 1u)) >> 16;  // RNE
  return (ushort)u;
}
__device__ __forceinline__ float bf2f(ushort b) {
  return __uint_as_float(((unsigned)b) << 16);
}
__device__ __forceinline__ float bflo(unsigned u) {
  return __uint_as_float(u << 16);
}
__device__ __forceinline__ float bfhi(unsigned u) {
  return __uint_as_float(u & 0xffff0000u);
}

// -------------------- W1 transpose+convert: [512][256] -> bf16 [256][512] --
__global__ __launch_bounds__(256) void w1t_kernel(const float* __restrict__ W1,
                                                  ushort* __restrict__ Bt) {
  int idx = blockIdx.x * 256 + threadIdx.x;  // 131072 total
  int k = idx >> 8, n = idx & 255;
  Bt[n * NFEAT + k] = f2bf(W1[idx]);
}

// ------------------------- GEMM1: bf16 MFMA -------------------------------
// C[M,256] = A[M,512] @ B[512,256]; A fp32 (convert in staging), B = W1t bf16.
// Block 256 thr = 4 waves (2x2), tile 128x128, BK=32, wave computes 64x64.
#define LDK 40  // padded LDS k-stride (bf16 elems): 2-way-max bank aliasing
__global__ __launch_bounds__(256) void gemm1_mfma(
    const float* __restrict__ A, const ushort* __restrict__ Bt,
    ushort* __restrict__ C, int M) {
  __shared__ ushort As[128 * LDK];
  __shared__ ushort Bs[128 * LDK];
  int tid = threadIdx.x;
  int wave = tid >> 6, lane = tid & 63;
  int bm = blockIdx.y * 128;
  int bn = blockIdx.x * 128;
  int wm = (wave & 1) * 64, wn = (wave >> 1) * 64;
  int lm = lane & 15;          // row (A) / col (B) within frag
  int lk = (lane >> 4) * 8;    // k offset within frag

  int arow = tid >> 1;             // 0..127
  int ahalf = (tid & 1) * 16;      // k sub-offset
  int brow = tid >> 2;             // 0..63
  int bq = (tid & 3) * 8;          // k sub-offset (8 bf16 = 16B)

  f32x4 acc[4][4] = {};

  const bool arv = (bm + arow) < M;
  const float* aptr = A + (size_t)(bm + arow) * NFEAT + ahalf;
  ushort* asp = &As[arow * LDK + ahalf];

  for (int k0 = 0; k0 < NFEAT; k0 += 32) {
    // stage A (fp32 -> bf16)
#pragma unroll
    for (int q = 0; q < 4; ++q) {
      float4 v = arv ? *(const float4*)(aptr + k0 + q * 4)
                     : make_float4(0.f, 0.f, 0.f, 0.f);
      ushort4 b;
      b.x = f2bf(v.x); b.y = f2bf(v.y); b.z = f2bf(v.z); b.w = f2bf(v.w);
      *(ushort4*)(asp + q * 4) = b;
    }
    // stage B (already bf16, n-major): 2 passes x 64 rows, 16B each
#pragma unroll
    for (int p = 0; p < 2; ++p) {
      int n = p * 64 + brow;
      *(uint4*)&Bs[n * LDK + bq] =
          *(const uint4*)&Bt[(size_t)(bn + n) * NFEAT + k0 + bq];
    }
    __syncthreads();
    s16x8 afr[4], bfr[4];
#pragma unroll
    for (int i = 0; i < 4; ++i)
      afr[i] = *(const s16x8*)&As[(wm + i * 16 + lm) * LDK + lk];
#pragma unroll
    for (int j = 0; j < 4; ++j)
      bfr[j] = *(const s16x8*)&Bs[(wn + j * 16 + lm) * LDK + lk];
#pragma unroll
    for (int i = 0; i < 4; ++i)
#pragma unroll
      for (int j = 0; j < 4; ++j)
        acc[i][j] = __builtin_amdgcn_mfma_f32_16x16x32_bf16(afr[i], bfr[j],
                                                            acc[i][j], 0, 0, 0);
    __syncthreads();
  }
  // epilogue: C/D layout col=lane&15, row=(lane>>4)*4+reg
  int ocol = bn + wn + lm;
  int orow0 = bm + wm + (lane >> 4) * 4;
#pragma unroll
  for (int i = 0; i < 4; ++i) {
#pragma unroll
    for (int r = 0; r < 4; ++r) {
      int row = orow0 + i * 16 + r;
      if (row < M) {
#pragma unroll
        for (int j = 0; j < 4; ++j)
          C[(size_t)row * NHID + ocol + j * 16] = f2bf(acc[i][j][r]);
      }
    }
  }
}

// ------------------------- CSR build --------------------------------------
__global__ __launch_bounds__(256) void hist_kernel(const int* __restrict__ dst,
                                                   int* __restrict__ deg, int E) {
  int e = blockIdx.x * 256 + threadIdx.x;
  if (e < E) atomicAdd(&deg[dst[e]], 1);
}

__global__ __launch_bounds__(256) void scan1_kernel(const int* __restrict__ deg,
                                                    int* __restrict__ part,
                                                    int* __restrict__ bsums, int M) {
  __shared__ int tmp[256];
  int t = threadIdx.x;
  int i = blockIdx.x * 256 + t;
  int v = (i < M) ? deg[i] : 0;
  tmp[t] = v;
  __syncthreads();
  for (int off = 1; off < 256; off <<= 1) {
    int add = (t >= off) ? tmp[t - off] : 0;
    __syncthreads();
    tmp[t] += add;
    __syncthreads();
  }
  if (i < M) part[i] = tmp[t];
  if (t == 255) bsums[blockIdx.x] = tmp[255];
}

__global__ __launch_bounds__(512) void scan2_kernel(int* __restrict__ bsums, int nb) {
  __shared__ int tmp[512];
  int t = threadIdx.x;
  int v = (t < nb) ? bsums[t] : 0;
  tmp[t] = v;
  __syncthreads();
  for (int off = 1; off < 512; off <<= 1) {
    int add = (t >= off) ? tmp[t - off] : 0;
    __syncthreads();
    tmp[t] += add;
    __syncthreads();
  }
  if (t < nb) bsums[t] = tmp[t];
}

__global__ __launch_bounds__(256) void scan3_kernel(
    const int* __restrict__ part, const int* __restrict__ bsums,
    const int* __restrict__ deg, int* __restrict__ rowptr,
    int* __restrict__ cursor, int M) {
  int i = blockIdx.x * 256 + threadIdx.x;
  if (i >= M) return;
  int incl = part[i] + (blockIdx.x > 0 ? bsums[blockIdx.x - 1] : 0);
  int start = incl - deg[i];
  rowptr[i] = start;
  cursor[i] = start;
}

// pack (src, weight-bits) into int2: one 8B random store per edge
__global__ __launch_bounds__(256) void scatter_kernel(
    const int* __restrict__ src, const int* __restrict__ dst,
    const float* __restrict__ w, int* __restrict__ cursor,
    int2* __restrict__ ep, int E) {
  int e = blockIdx.x * 256 + threadIdx.x;
  if (e >= E) return;
  int d = dst[e];
  int pos = atomicAdd(&cursor[d], 1);
  ep[pos] = make_int2(src[e], __float_as_int(w[e]));
}

// ---------------- SpMM1 (CSR): one block per dst node, bf16 in/out --------
__global__ __launch_bounds__(256) void spmm1_csr_kernel(
    const ushort* __restrict__ S, const int* __restrict__ rowptr,
    const int* __restrict__ deg, const int2* __restrict__ ep,
    const float* __restrict__ b1, ushort* __restrict__ h, int M) {
  int node = blockIdx.x;
  int f = threadIdx.x;
  int beg = rowptr[node];
  int n = deg[node];
  __shared__ int2 s_e[64];
  float acc = 0.f;
  for (int j0 = 0; j0 < n; j0 += 64) {
    int cnt = min(64, n - j0);
    if (threadIdx.x < cnt) s_e[threadIdx.x] = ep[beg + j0 + threadIdx.x];
    __syncthreads();
    int j = 0;
    for (; j + 4 <= cnt; j += 4) {
      int2 e0 = s_e[j + 0], e1 = s_e[j + 1], e2 = s_e[j + 2], e3 = s_e[j + 3];
      float v0 = bf2f(S[(size_t)e0.x * NHID + f]);
      float v1 = bf2f(S[(size_t)e1.x * NHID + f]);
      float v2 = bf2f(S[(size_t)e2.x * NHID + f]);
      float v3 = bf2f(S[(size_t)e3.x * NHID + f]);
      acc += __int_as_float(e0.y) * v0;
      acc += __int_as_float(e1.y) * v1;
      acc += __int_as_float(e2.y) * v2;
      acc += __int_as_float(e3.y) * v3;
    }
    for (; j < cnt; ++j)
      acc += __int_as_float(s_e[j].y) * bf2f(S[(size_t)s_e[j].x * NHID + f]);
    __syncthreads();
  }
  h[(size_t)node * NHID + f] = f2bf(fmaxf(acc + b1[f], 0.f));
}

// ------------------- GEMM2: h(bf16) @ W2, W2 in LDS -----------------------
__global__ __launch_bounds__(256) void gemm2_kernel(
    const ushort* __restrict__ H, const float* __restrict__ W2,
    float* __restrict__ S2, int M) {
  __shared__ float W2s[NHID * NCLASS];
  for (int i = threadIdx.x; i < NHID * NCLASS; i += 256) W2s[i] = W2[i];
  __syncthreads();
  int row = blockIdx.x * 256 + threadIdx.x;
  if (row >= M) return;
  const float4* W2v = (const float4*)W2s;  // row k: 10 float4
  float4 acc[10];
#pragma unroll
  for (int j = 0; j < 10; ++j) acc[j] = make_float4(0.f, 0.f, 0.f, 0.f);
  const uint4* hp = (const uint4*)(H + (size_t)row * NHID);  // 32 x uint4
  for (int kb = 0; kb < 32; ++kb) {
    uint4 u = hp[kb];
    float a[8] = {bflo(u.x), bfhi(u.x), bflo(u.y), bfhi(u.y),
                  bflo(u.z), bfhi(u.z), bflo(u.w), bfhi(u.w)};
#pragma unroll
    for (int kk = 0; kk < 8; ++kk) {
#pragma unroll
      for (int j = 0; j < 10; ++j) {
        float4 wv = W2v[(kb * 8 + kk) * 10 + j];
        acc[j].x += a[kk] * wv.x;
        acc[j].y += a[kk] * wv.y;
        acc[j].z += a[kk] * wv.z;
        acc[j].w += a[kk] * wv.w;
      }
    }
  }
  float4* out = (float4*)(S2 + (size_t)row * NCLASS);
#pragma unroll
  for (int j = 0; j < 10; ++j) out[j] = acc[j];
}

// -------- SpMM2 (CSR) + bias + log_softmax, one wave per dst node ---------
__global__ __launch_bounds__(256) void spmm2_csr_kernel(
    const float* __restrict__ S2, const int* __restrict__ rowptr,
    const int* __restrict__ deg, const int2* __restrict__ ep,
    const float* __restrict__ b2, float* __restrict__ out, int M) {
  int wid = (blockIdx.x * 256 + threadIdx.x) >> 6;
  int lane = threadIdx.x & 63;
  if (wid >= M) return;
  int beg = rowptr[wid];
  int n = deg[wid];
  float acc = 0.f;
  for (int j0 = 0; j0 < n; j0 += 64) {
    int cnt = min(64, n - j0);
    int msrc = 0;
    float mw = 0.f;
    if (lane < cnt) {
      int2 e = ep[beg + j0 + lane];
      msrc = e.x;
      mw = __int_as_float(e.y);
    }
    for (int j = 0; j < cnt; ++j) {
      int s = __shfl(msrc, j);
      float wt = __shfl(mw, j);
      if (lane < NCLASS) acc += wt * S2[(size_t)s * NCLASS + lane];
    }
  }
  float v = (lane < NCLASS) ? acc + b2[lane] : -INFINITY;
  float m = v;
#pragma unroll
  for (int off = 32; off; off >>= 1) m = fmaxf(m, __shfl_xor(m, off));
  float ex = (lane < NCLASS) ? __expf(v - m) : 0.f;
  float s = ex;
#pragma unroll
  for (int off = 32; off; off >>= 1) s += __shfl_xor(s, off);
  float lse = m + __logf(s);
  if (lane < NCLASS) out[(size_t)wid * NCLASS + lane] = v - lse;
}

// ---------------------------------------------------------------------------
extern "C" void kernel_launch(void* const* d_in, const int* in_sizes, int n_in,
                              void* d_out, int out_size, void* d_ws,
                              size_t ws_size, hipStream_t stream) {
  const float* x  = (const float*)d_in[0];
  const int* esrc = (const int*)d_in[1];
  const int* edst = (const int*)d_in[2];
  const float* ew = (const float*)d_in[3];
  const float* W1 = (const float*)d_in[4];
  const float* b1 = (const float*)d_in[5];
  const float* W2 = (const float*)d_in[6];
  const float* b2 = (const float*)d_in[7];
  float* out = (float*)d_out;

  const int M = in_sizes[0] / NFEAT;  // 100000
  const int E = in_sizes[1];          // 3200000

  // workspace layout (all 16B-aligned offsets)
  char* p = (char*)d_ws;
  ushort* support1 = (ushort*)p;           p += (size_t)M * NHID * 2;    // 51.2 MB
  ushort* h        = (ushort*)p;           p += (size_t)M * NHID * 2;    // 51.2 MB
  float*  support2 = (float*)p;            p += (size_t)M * NCLASS * 4;  // 16 MB
  ushort* W1t      = (ushort*)p;           p += (size_t)NFEAT * NHID * 2;// 0.26 MB
  int*    deg      = (int*)p;              p += (size_t)M * 4;
  int*    part     = (int*)p;              p += (size_t)M * 4;
  int*    rowptr   = (int*)p;              p += (size_t)M * 4;
  int*    cursor   = (int*)p;              p += (size_t)M * 4;
  int*    bsums    = (int*)p;              p += 512 * 4;
  int2*   ep       = (int2*)p;             // 25.6 MB

  const int nbScan = (M + 255) / 256;  // 391 <= 512

  // ---- CSR build ----
  hipMemsetAsync(deg, 0, (size_t)M * sizeof(int), stream);
  hist_kernel<<<(E + 255) / 256, 256, 0, stream>>>(edst, deg, E);
  scan1_kernel<<<nbScan, 256, 0, stream>>>(deg, part, bsums, M);
  scan2_kernel<<<1, 512, 0, stream>>>(bsums, nbScan);
  scan3_kernel<<<nbScan, 256, 0, stream>>>(part, bsums, deg, rowptr, cursor, M);
  scatter_kernel<<<(E + 255) / 256, 256, 0, stream>>>(esrc, edst, ew, cursor,
                                                      ep, E);

  // ---- layer 1 ----
  w1t_kernel<<<(NFEAT * NHID) / 256, 256, 0, stream>>>(W1, W1t);
  dim3 g1(NHID / 128, (M + 127) / 128);
  gemm1_mfma<<<g1, 256, 0, stream>>>(x, W1t, support1, M);
  spmm1_csr_kernel<<<M, 256, 0, stream>>>(support1, rowptr, deg, ep, b1, h, M);

  // ---- layer 2 ----
  gemm2_kernel<<<(M + 255) / 256, 256, 0, stream>>>(h, W2, support2, M);
  spmm2_csr_kernel<<<(M * 64 + 255) / 256, 256, 0, stream>>>(
      support2, rowptr, deg, ep, b2, out, M);
}

// Round 4
// 1213.249 us; speedup vs baseline: 3.0848x; 1.0299x over previous
//
#include <hip/hip_runtime.h>
#include <hip/hip_bf16.h>
#include <math.h>

// ---------------------------------------------------------------------------
// GCN 2-layer forward, CSR aggregation + bf16 MFMA GEMM1 + bf16 activations.
//   W1t      = transpose(W1) as bf16 [256][512]
//   support1 = x @ W1            (MFMA bf16, out bf16)
//   h        = relu(agg(support1) + b1)   bf16   [wave/node, uint2 gathers]
//   support2 = h @ W2            (per-row fp32 acc, bf16 out, W2 in LDS)
//   out      = log_softmax(agg(support2) + b2)   [wave/node, uint gathers]
// ---------------------------------------------------------------------------

#define NFEAT 512
#define NHID  256
#define NCLASS 40

typedef __attribute__((ext_vector_type(4))) float f32x4;
typedef __attribute__((ext_vector_type(8))) short s16x8;

__device__ __forceinline__ ushort f2bf(float f) {
  unsigned u = __float_as_uint(f);
  u = (u + 0x7fffu + ((u >> 16) & 1u)) >> 16;  // RNE
  return (ushort)u;
}
__device__ __forceinline__ float bflo(unsigned u) {
  return __uint_as_float(u << 16);
}
__device__ __forceinline__ float bfhi(unsigned u) {
  return __uint_as_float(u & 0xffff0000u);
}

// -------------------- W1 transpose+convert: [512][256] -> bf16 [256][512] --
__global__ __launch_bounds__(256) void w1t_kernel(const float* __restrict__ W1,
                                                  ushort* __restrict__ Bt) {
  int idx = blockIdx.x * 256 + threadIdx.x;  // 131072 total
  int k = idx >> 8, n = idx & 255;
  Bt[n * NFEAT + k] = f2bf(W1[idx]);
}

// ------------------------- GEMM1: bf16 MFMA -------------------------------
// Block 256 thr = 4 waves (2x2), tile 128x128, BK=32, wave computes 64x64.
#define LDK 40  // padded LDS k-stride (bf16): max 2-way bank aliasing (free)
__global__ __launch_bounds__(256) void gemm1_mfma(
    const float* __restrict__ A, const ushort* __restrict__ Bt,
    ushort* __restrict__ C, int M) {
  __shared__ ushort As[128 * LDK];
  __shared__ ushort Bs[128 * LDK];
  int tid = threadIdx.x;
  int wave = tid >> 6, lane = tid & 63;
  int bm = blockIdx.y * 128;
  int bn = blockIdx.x * 128;
  int wm = (wave & 1) * 64, wn = (wave >> 1) * 64;
  int lm = lane & 15;
  int lk = (lane >> 4) * 8;

  int arow = tid >> 1;
  int ahalf = (tid & 1) * 16;
  int brow = tid >> 2;
  int bq = (tid & 3) * 8;

  f32x4 acc[4][4] = {};

  const bool arv = (bm + arow) < M;
  const float* aptr = A + (size_t)(bm + arow) * NFEAT + ahalf;
  ushort* asp = &As[arow * LDK + ahalf];

  for (int k0 = 0; k0 < NFEAT; k0 += 32) {
#pragma unroll
    for (int q = 0; q < 4; ++q) {
      float4 v = arv ? *(const float4*)(aptr + k0 + q * 4)
                     : make_float4(0.f, 0.f, 0.f, 0.f);
      ushort4 b;
      b.x = f2bf(v.x); b.y = f2bf(v.y); b.z = f2bf(v.z); b.w = f2bf(v.w);
      *(ushort4*)(asp + q * 4) = b;
    }
#pragma unroll
    for (int p = 0; p < 2; ++p) {
      int n = p * 64 + brow;
      *(uint4*)&Bs[n * LDK + bq] =
          *(const uint4*)&Bt[(size_t)(bn + n) * NFEAT + k0 + bq];
    }
    __syncthreads();
    s16x8 afr[4], bfr[4];
#pragma unroll
    for (int i = 0; i < 4; ++i)
      afr[i] = *(const s16x8*)&As[(wm + i * 16 + lm) * LDK + lk];
#pragma unroll
    for (int j = 0; j < 4; ++j)
      bfr[j] = *(const s16x8*)&Bs[(wn + j * 16 + lm) * LDK + lk];
#pragma unroll
    for (int i = 0; i < 4; ++i)
#pragma unroll
      for (int j = 0; j < 4; ++j)
        acc[i][j] = __builtin_amdgcn_mfma_f32_16x16x32_bf16(afr[i], bfr[j],
                                                            acc[i][j], 0, 0, 0);
    __syncthreads();
  }
  int ocol = bn + wn + lm;
  int orow0 = bm + wm + (lane >> 4) * 4;
#pragma unroll
  for (int i = 0; i < 4; ++i) {
#pragma unroll
    for (int r = 0; r < 4; ++r) {
      int row = orow0 + i * 16 + r;
      if (row < M) {
#pragma unroll
        for (int j = 0; j < 4; ++j)
          C[(size_t)row * NHID + ocol + j * 16] = f2bf(acc[i][j][r]);
      }
    }
  }
}

// ------------------------- CSR build --------------------------------------
__global__ __launch_bounds__(256) void hist_kernel(const int* __restrict__ dst,
                                                   int* __restrict__ deg, int E) {
  int e = blockIdx.x * 256 + threadIdx.x;
  if (e < E) atomicAdd(&deg[dst[e]], 1);
}

__global__ __launch_bounds__(256) void scan1_kernel(const int* __restrict__ deg,
                                                    int* __restrict__ part,
                                                    int* __restrict__ bsums, int M) {
  __shared__ int tmp[256];
  int t = threadIdx.x;
  int i = blockIdx.x * 256 + t;
  int v = (i < M) ? deg[i] : 0;
  tmp[t] = v;
  __syncthreads();
  for (int off = 1; off < 256; off <<= 1) {
    int add = (t >= off) ? tmp[t - off] : 0;
    __syncthreads();
    tmp[t] += add;
    __syncthreads();
  }
  if (i < M) part[i] = tmp[t];
  if (t == 255) bsums[blockIdx.x] = tmp[255];
}

__global__ __launch_bounds__(512) void scan2_kernel(int* __restrict__ bsums, int nb) {
  __shared__ int tmp[512];
  int t = threadIdx.x;
  int v = (t < nb) ? bsums[t] : 0;
  tmp[t] = v;
  __syncthreads();
  for (int off = 1; off < 512; off <<= 1) {
    int add = (t >= off) ? tmp[t - off] : 0;
    __syncthreads();
    tmp[t] += add;
    __syncthreads();
  }
  if (t < nb) bsums[t] = tmp[t];
}

__global__ __launch_bounds__(256) void scan3_kernel(
    const int* __restrict__ part, const int* __restrict__ bsums,
    const int* __restrict__ deg, int* __restrict__ rowptr,
    int* __restrict__ cursor, int M) {
  int i = blockIdx.x * 256 + threadIdx.x;
  if (i >= M) return;
  int incl = part[i] + (blockIdx.x > 0 ? bsums[blockIdx.x - 1] : 0);
  int start = incl - deg[i];
  rowptr[i] = start;
  cursor[i] = start;
}

__global__ __launch_bounds__(256) void scatter_kernel(
    const int* __restrict__ src, const int* __restrict__ dst,
    const float* __restrict__ w, int* __restrict__ cursor,
    int2* __restrict__ ep, int E) {
  int e = blockIdx.x * 256 + threadIdx.x;
  if (e >= E) return;
  int d = dst[e];
  int pos = atomicAdd(&cursor[d], 1);
  ep[pos] = make_int2(src[e], __float_as_int(w[e]));
}

// ---------------- SpMM1 (CSR): one WAVE per dst node, uint2 gathers -------
// h[node][f] = relu(sum_j w_j * S[src_j][f] + b1[f]); lane owns 4 feats.
__global__ __launch_bounds__(256) void spmm1_csr_kernel(
    const ushort* __restrict__ S, const int* __restrict__ rowptr,
    const int* __restrict__ deg, const int2* __restrict__ ep,
    const float* __restrict__ b1, ushort* __restrict__ h, int M) {
  int wid = (blockIdx.x * 256 + threadIdx.x) >> 6;  // node
  int lane = threadIdx.x & 63;
  if (wid >= M) return;
  int beg = rowptr[wid];
  int n = deg[wid];
  const ushort* Sl = S + (size_t)lane * 4;  // lane's 8B column slice
  float acc0 = 0.f, acc1 = 0.f, acc2 = 0.f, acc3 = 0.f;
  for (int j0 = 0; j0 < n; j0 += 64) {
    int cnt = min(64, n - j0);
    int msrc = 0;
    float mw = 0.f;
    if (lane < cnt) {
      int2 e = ep[beg + j0 + lane];
      msrc = e.x;
      mw = __int_as_float(e.y);
    }
    for (int j = 0; j < cnt; ++j) {
      int s = __shfl(msrc, j);      // uniform idx -> readlane (SGPR)
      float wt = __shfl(mw, j);
      uint2 u = *(const uint2*)(Sl + ((size_t)s << 8));
      acc0 += wt * bflo(u.x);
      acc1 += wt * bfhi(u.x);
      acc2 += wt * bflo(u.y);
      acc3 += wt * bfhi(u.y);
    }
  }
  float4 b = *(const float4*)(b1 + lane * 4);
  ushort4 o;
  o.x = f2bf(fmaxf(acc0 + b.x, 0.f));
  o.y = f2bf(fmaxf(acc1 + b.y, 0.f));
  o.z = f2bf(fmaxf(acc2 + b.z, 0.f));
  o.w = f2bf(fmaxf(acc3 + b.w, 0.f));
  *(ushort4*)(h + ((size_t)wid << 8) + lane * 4) = o;
}

// ------------------- GEMM2: h(bf16) @ W2 -> bf16, W2 in LDS ---------------
__global__ __launch_bounds__(256) void gemm2_kernel(
    const ushort* __restrict__ H, const float* __restrict__ W2,
    ushort* __restrict__ S2, int M) {
  __shared__ float W2s[NHID * NCLASS];
  for (int i = threadIdx.x; i < NHID * NCLASS; i += 256) W2s[i] = W2[i];
  __syncthreads();
  int row = blockIdx.x * 256 + threadIdx.x;
  if (row >= M) return;
  const float4* W2v = (const float4*)W2s;
  float4 acc[10];
#pragma unroll
  for (int j = 0; j < 10; ++j) acc[j] = make_float4(0.f, 0.f, 0.f, 0.f);
  const uint4* hp = (const uint4*)(H + (size_t)row * NHID);
  for (int kb = 0; kb < 32; ++kb) {
    uint4 u = hp[kb];
    float a[8] = {bflo(u.x), bfhi(u.x), bflo(u.y), bfhi(u.y),
                  bflo(u.z), bfhi(u.z), bflo(u.w), bfhi(u.w)};
#pragma unroll
    for (int kk = 0; kk < 8; ++kk) {
#pragma unroll
      for (int j = 0; j < 10; ++j) {
        float4 wv = W2v[(kb * 8 + kk) * 10 + j];
        acc[j].x += a[kk] * wv.x;
        acc[j].y += a[kk] * wv.y;
        acc[j].z += a[kk] * wv.z;
        acc[j].w += a[kk] * wv.w;
      }
    }
  }
  uint2* outp = (uint2*)(S2 + (size_t)row * NCLASS);  // 80B row, 8B aligned
#pragma unroll
  for (int j = 0; j < 10; j += 2) {
    uint2 o0, o1;
    o0.x = (unsigned)f2bf(acc[j].x) | ((unsigned)f2bf(acc[j].y) << 16);
    o0.y = (unsigned)f2bf(acc[j].z) | ((unsigned)f2bf(acc[j].w) << 16);
    o1.x = (unsigned)f2bf(acc[j + 1].x) | ((unsigned)f2bf(acc[j + 1].y) << 16);
    o1.y = (unsigned)f2bf(acc[j + 1].z) | ((unsigned)f2bf(acc[j + 1].w) << 16);
    outp[j] = o0;
    outp[j + 1] = o1;
  }
}

// -------- SpMM2 (CSR, bf16) + bias + log_softmax, one wave per node -------
__global__ __launch_bounds__(256) void spmm2_csr_kernel(
    const ushort* __restrict__ S2, const int* __restrict__ rowptr,
    const int* __restrict__ deg, const int2* __restrict__ ep,
    const float* __restrict__ b2, float* __restrict__ out, int M) {
  int wid = (blockIdx.x * 256 + threadIdx.x) >> 6;
  int lane = threadIdx.x & 63;
  if (wid >= M) return;
  int beg = rowptr[wid];
  int n = deg[wid];
  float acc0 = 0.f, acc1 = 0.f;  // lane<20 owns feats {2*lane, 2*lane+1}
  const ushort* S2l = S2 + lane * 2;
  for (int j0 = 0; j0 < n; j0 += 64) {
    int cnt = min(64, n - j0);
    int msrc = 0;
    float mw = 0.f;
    if (lane < cnt) {
      int2 e = ep[beg + j0 + lane];
      msrc = e.x;
      mw = __int_as_float(e.y);
    }
    for (int j = 0; j < cnt; ++j) {
      int s = __shfl(msrc, j);
      float wt = __shfl(mw, j);
      if (lane < 20) {
        unsigned u = *(const unsigned*)(S2l + (size_t)s * NCLASS);
        acc0 += wt * bflo(u);
        acc1 += wt * bfhi(u);
      }
    }
  }
  float v0 = -INFINITY, v1 = -INFINITY;
  if (lane < 20) {
    float2 b = *(const float2*)(b2 + lane * 2);
    v0 = acc0 + b.x;
    v1 = acc1 + b.y;
  }
  float m = fmaxf(v0, v1);
#pragma unroll
  for (int off = 32; off; off >>= 1) m = fmaxf(m, __shfl_xor(m, off));
  float ex = (lane < 20) ? __expf(v0 - m) + __expf(v1 - m) : 0.f;
  float s = ex;
#pragma unroll
  for (int off = 32; off; off >>= 1) s += __shfl_xor(s, off);
  float lse = m + __logf(s);
  if (lane < 20) {
    float2 o = {v0 - lse, v1 - lse};
    *(float2*)(out + (size_t)wid * NCLASS + lane * 2) = o;
  }
}

// ---------------------------------------------------------------------------
extern "C" void kernel_launch(void* const* d_in, const int* in_sizes, int n_in,
                              void* d_out, int out_size, void* d_ws,
                              size_t ws_size, hipStream_t stream) {
  const float* x  = (const float*)d_in[0];
  const int* esrc = (const int*)d_in[1];
  const int* edst = (const int*)d_in[2];
  const float* ew = (const float*)d_in[3];
  const float* W1 = (const float*)d_in[4];
  const float* b1 = (const float*)d_in[5];
  const float* W2 = (const float*)d_in[6];
  const float* b2 = (const float*)d_in[7];
  float* out = (float*)d_out;

  const int M = in_sizes[0] / NFEAT;  // 100000
  const int E = in_sizes[1];          // 3200000

  char* p = (char*)d_ws;
  ushort* support1 = (ushort*)p;           p += (size_t)M * NHID * 2;
  ushort* h        = (ushort*)p;           p += (size_t)M * NHID * 2;
  ushort* support2 = (ushort*)p;           p += (size_t)M * NCLASS * 2;
  ushort* W1t      = (ushort*)p;           p += (size_t)NFEAT * NHID * 2;
  int*    deg      = (int*)p;              p += (size_t)M * 4;
  int*    part     = (int*)p;              p += (size_t)M * 4;
  int*    rowptr   = (int*)p;              p += (size_t)M * 4;
  int*    cursor   = (int*)p;              p += (size_t)M * 4;
  int*    bsums    = (int*)p;              p += 512 * 4;
  int2*   ep       = (int2*)p;

  const int nbScan = (M + 255) / 256;  // 391 <= 512

  // ---- CSR build ----
  hipMemsetAsync(deg, 0, (size_t)M * sizeof(int), stream);
  hist_kernel<<<(E + 255) / 256, 256, 0, stream>>>(edst, deg, E);
  scan1_kernel<<<nbScan, 256, 0, stream>>>(deg, part, bsums, M);
  scan2_kernel<<<1, 512, 0, stream>>>(bsums, nbScan);
  scan3_kernel<<<nbScan, 256, 0, stream>>>(part, bsums, deg, rowptr, cursor, M);
  scatter_kernel<<<(E + 255) / 256, 256, 0, stream>>>(esrc, edst, ew, cursor,
                                                      ep, E);

  // ---- layer 1 ----
  w1t_kernel<<<(NFEAT * NHID) / 256, 256, 0, stream>>>(W1, W1t);
  dim3 g1(NHID / 128, (M + 127) / 128);
  gemm1_mfma<<<g1, 256, 0, stream>>>(x, W1t, support1, M);
  spmm1_csr_kernel<<<(M * 64 + 255) / 256, 256, 0, stream>>>(
      support1, rowptr, deg, ep, b1, h, M);

  // ---- layer 2 ----
  gemm2_kernel<<<(M + 255) / 256, 256, 0, stream>>>(h, W2, support2, M);
  spmm2_csr_kernel<<<(M * 64 + 255) / 256, 256, 0, stream>>>(
      support2, rowptr, deg, ep, b2, out, M);
}

// Round 5
// 1123.069 us; speedup vs baseline: 3.3325x; 1.0803x over previous
//
#include <hip/hip_runtime.h>
#include <hip/hip_bf16.h>
#include <math.h>

// ---------------------------------------------------------------------------
// GCN 2-layer forward, CSR aggregation + bf16 MFMA GEMM1 + bf16 activations.
// CSR build uses a two-phase bucketed counting sort (bucket = 512 dst nodes)
// to avoid cross-XCD random-store write amplification (R4: 198MB writes for
// a 25.6MB array) and 3.2M global atomics.
// ---------------------------------------------------------------------------

#define NFEAT 512
#define NHID  256
#define NCLASS 40
#define BKT_SHIFT 9
#define BKT_NODES 512
#define MAX_BKT 256      // >= ceil(100000/512)=196
#define BIN_EPB 4096     // edges per binA block

typedef __attribute__((ext_vector_type(4))) float f32x4;
typedef __attribute__((ext_vector_type(8))) short s16x8;

__device__ __forceinline__ ushort f2bf(float f) {
  unsigned u = __float_as_uint(f);
  u = (u + 0x7fffu + ((u >> 16) & 1u)) >> 16;  // RNE
  return (ushort)u;
}
__device__ __forceinline__ float bflo(unsigned u) {
  return __uint_as_float(u << 16);
}
__device__ __forceinline__ float bfhi(unsigned u) {
  return __uint_as_float(u & 0xffff0000u);
}

// -------------------- W1 transpose+convert: [512][256] -> bf16 [256][512] --
__global__ __launch_bounds__(256) void w1t_kernel(const float* __restrict__ W1,
                                                  ushort* __restrict__ Bt) {
  int idx = blockIdx.x * 256 + threadIdx.x;
  int k = idx >> 8, n = idx & 255;
  Bt[n * NFEAT + k] = f2bf(W1[idx]);
}

// ------------------------- GEMM1: bf16 MFMA -------------------------------
#define LDK 40  // padded LDS k-stride (bf16): max 2-way bank aliasing (free)
__global__ __launch_bounds__(256) void gemm1_mfma(
    const float* __restrict__ A, const ushort* __restrict__ Bt,
    ushort* __restrict__ C, int M) {
  __shared__ ushort As[128 * LDK];
  __shared__ ushort Bs[128 * LDK];
  int tid = threadIdx.x;
  int wave = tid >> 6, lane = tid & 63;
  int bm = blockIdx.y * 128;
  int bn = blockIdx.x * 128;
  int wm = (wave & 1) * 64, wn = (wave >> 1) * 64;
  int lm = lane & 15;
  int lk = (lane >> 4) * 8;

  int arow = tid >> 1;
  int ahalf = (tid & 1) * 16;
  int brow = tid >> 2;
  int bq = (tid & 3) * 8;

  f32x4 acc[4][4] = {};

  const bool arv = (bm + arow) < M;
  const float* aptr = A + (size_t)(bm + arow) * NFEAT + ahalf;
  ushort* asp = &As[arow * LDK + ahalf];

  for (int k0 = 0; k0 < NFEAT; k0 += 32) {
#pragma unroll
    for (int q = 0; q < 4; ++q) {
      float4 v = arv ? *(const float4*)(aptr + k0 + q * 4)
                     : make_float4(0.f, 0.f, 0.f, 0.f);
      ushort4 b;
      b.x = f2bf(v.x); b.y = f2bf(v.y); b.z = f2bf(v.z); b.w = f2bf(v.w);
      *(ushort4*)(asp + q * 4) = b;
    }
#pragma unroll
    for (int p = 0; p < 2; ++p) {
      int n = p * 64 + brow;
      *(uint4*)&Bs[n * LDK + bq] =
          *(const uint4*)&Bt[(size_t)(bn + n) * NFEAT + k0 + bq];
    }
    __syncthreads();
    s16x8 afr[4], bfr[4];
#pragma unroll
    for (int i = 0; i < 4; ++i)
      afr[i] = *(const s16x8*)&As[(wm + i * 16 + lm) * LDK + lk];
#pragma unroll
    for (int j = 0; j < 4; ++j)
      bfr[j] = *(const s16x8*)&Bs[(wn + j * 16 + lm) * LDK + lk];
#pragma unroll
    for (int i = 0; i < 4; ++i)
#pragma unroll
      for (int j = 0; j < 4; ++j)
        acc[i][j] = __builtin_amdgcn_mfma_f32_16x16x32_bf16(afr[i], bfr[j],
                                                            acc[i][j], 0, 0, 0);
    __syncthreads();
  }
  int ocol = bn + wn + lm;
  int orow0 = bm + wm + (lane >> 4) * 4;
#pragma unroll
  for (int i = 0; i < 4; ++i) {
#pragma unroll
    for (int r = 0; r < 4; ++r) {
      int row = orow0 + i * 16 + r;
      if (row < M) {
#pragma unroll
        for (int j = 0; j < 4; ++j)
          C[(size_t)row * NHID + ocol + j * 16] = f2bf(acc[i][j][r]);
      }
    }
  }
}

// ------------------------- CSR build --------------------------------------
__global__ __launch_bounds__(256) void hist_kernel(const int* __restrict__ dst,
                                                   int* __restrict__ deg, int E) {
  int e = blockIdx.x * 256 + threadIdx.x;
  if (e < E) atomicAdd(&deg[dst[e]], 1);
}

__global__ __launch_bounds__(256) void scan1_kernel(const int* __restrict__ deg,
                                                    int* __restrict__ part,
                                                    int* __restrict__ bsums, int M) {
  __shared__ int tmp[256];
  int t = threadIdx.x;
  int i = blockIdx.x * 256 + t;
  int v = (i < M) ? deg[i] : 0;
  tmp[t] = v;
  __syncthreads();
  for (int off = 1; off < 256; off <<= 1) {
    int add = (t >= off) ? tmp[t - off] : 0;
    __syncthreads();
    tmp[t] += add;
    __syncthreads();
  }
  if (i < M) part[i] = tmp[t];
  if (t == 255) bsums[blockIdx.x] = tmp[255];
}

__global__ __launch_bounds__(512) void scan2_kernel(int* __restrict__ bsums, int nb) {
  __shared__ int tmp[512];
  int t = threadIdx.x;
  int v = (t < nb) ? bsums[t] : 0;
  tmp[t] = v;
  __syncthreads();
  for (int off = 1; off < 512; off <<= 1) {
    int add = (t >= off) ? tmp[t - off] : 0;
    __syncthreads();
    tmp[t] += add;
    __syncthreads();
  }
  if (t < nb) bsums[t] = tmp[t];
}

__global__ __launch_bounds__(256) void scan3_kernel(
    const int* __restrict__ part, const int* __restrict__ bsums,
    const int* __restrict__ deg, int* __restrict__ rowptr, int M) {
  int i = blockIdx.x * 256 + threadIdx.x;
  if (i >= M) return;
  int incl = part[i] + (blockIdx.x > 0 ? bsums[blockIdx.x - 1] : 0);
  rowptr[i] = incl - deg[i];
}

// bucket cursors: gcursor[b] = rowptr[b*512]
__global__ __launch_bounds__(256) void initcur_kernel(
    const int* __restrict__ rowptr, int* __restrict__ gcursor, int nbkt) {
  int b = threadIdx.x;
  if (b < nbkt) gcursor[b] = rowptr[b * BKT_NODES];
}

// binA: bucket-major binning. Per-block LDS histogram -> one global reserve
// per (block,bucket) -> write (src,w) int2 + dst-low ushort into tmp.
__global__ __launch_bounds__(256) void binA_kernel(
    const int* __restrict__ esrc, const int* __restrict__ edst,
    const float* __restrict__ ew, int* __restrict__ gcursor,
    int2* __restrict__ tmp_sw, ushort* __restrict__ tmp_d, int E) {
  __shared__ int hist[MAX_BKT];
  int t = threadIdx.x;
  for (int i = t; i < MAX_BKT; i += 256) hist[i] = 0;
  __syncthreads();
  int e0 = blockIdx.x * BIN_EPB;
#pragma unroll
  for (int k = 0; k < BIN_EPB / 256; ++k) {
    int e = e0 + k * 256 + t;
    if (e < E) atomicAdd(&hist[edst[e] >> BKT_SHIFT], 1);
  }
  __syncthreads();
  // reserve: hist[b] becomes this block's running cursor (global base)
  for (int i = t; i < MAX_BKT; i += 256) {
    int c = hist[i];
    hist[i] = c ? atomicAdd(&gcursor[i], c) : 0;
  }
  __syncthreads();
#pragma unroll
  for (int k = 0; k < BIN_EPB / 256; ++k) {
    int e = e0 + k * 256 + t;
    if (e < E) {
      int d = edst[e];
      int b = d >> BKT_SHIFT;
      int pos = atomicAdd(&hist[b], 1);
      tmp_sw[pos] = make_int2(esrc[e], __float_as_int(ew[e]));
      tmp_d[pos] = (ushort)(d & (BKT_NODES - 1));
    }
  }
}

// binB: one block per bucket; LDS per-node cursors; dense region in -> dense
// region out (final CSR edge order).
__global__ __launch_bounds__(512) void binB_kernel(
    const int2* __restrict__ tmp_sw, const ushort* __restrict__ tmp_d,
    const int* __restrict__ rowptr, int2* __restrict__ ep, int M, int E) {
  __shared__ int cur[BKT_NODES];
  int b = blockIdx.x;
  int nbase = b * BKT_NODES;
  for (int i = threadIdx.x; i < BKT_NODES; i += 512) {
    int node = nbase + i;
    cur[i] = (node < M) ? rowptr[node] : 0;
  }
  __syncthreads();
  int start = rowptr[nbase];
  int nend = nbase + BKT_NODES;
  int end = (nend < M) ? rowptr[nend] : E;
  for (int i = start + threadIdx.x; i < end; i += 512) {
    int2 sw = tmp_sw[i];
    int dl = tmp_d[i];
    int pos = atomicAdd(&cur[dl], 1);
    ep[pos] = sw;
  }
}

// ---------------- SpMM1 (CSR): one WAVE per dst node, uint2 gathers -------
__global__ __launch_bounds__(256) void spmm1_csr_kernel(
    const ushort* __restrict__ S, const int* __restrict__ rowptr,
    const int* __restrict__ deg, const int2* __restrict__ ep,
    const float* __restrict__ b1, ushort* __restrict__ h, int M) {
  int wid = (blockIdx.x * 256 + threadIdx.x) >> 6;
  int lane = threadIdx.x & 63;
  if (wid >= M) return;
  int beg = rowptr[wid];
  int n = deg[wid];
  const ushort* Sl = S + (size_t)lane * 4;
  float acc0 = 0.f, acc1 = 0.f, acc2 = 0.f, acc3 = 0.f;
  for (int j0 = 0; j0 < n; j0 += 64) {
    int cnt = min(64, n - j0);
    int msrc = 0;
    float mw = 0.f;
    if (lane < cnt) {
      int2 e = ep[beg + j0 + lane];
      msrc = e.x;
      mw = __int_as_float(e.y);
    }
    for (int j = 0; j < cnt; ++j) {
      int s = __shfl(msrc, j);
      float wt = __shfl(mw, j);
      uint2 u = *(const uint2*)(Sl + ((size_t)s << 8));
      acc0 += wt * bflo(u.x);
      acc1 += wt * bfhi(u.x);
      acc2 += wt * bflo(u.y);
      acc3 += wt * bfhi(u.y);
    }
  }
  float4 b = *(const float4*)(b1 + lane * 4);
  ushort4 o;
  o.x = f2bf(fmaxf(acc0 + b.x, 0.f));
  o.y = f2bf(fmaxf(acc1 + b.y, 0.f));
  o.z = f2bf(fmaxf(acc2 + b.z, 0.f));
  o.w = f2bf(fmaxf(acc3 + b.w, 0.f));
  *(ushort4*)(h + ((size_t)wid << 8) + lane * 4) = o;
}

// ------------------- GEMM2: h(bf16) @ W2 -> bf16, W2 in LDS ---------------
__global__ __launch_bounds__(256) void gemm2_kernel(
    const ushort* __restrict__ H, const float* __restrict__ W2,
    ushort* __restrict__ S2, int M) {
  __shared__ float W2s[NHID * NCLASS];
  for (int i = threadIdx.x; i < NHID * NCLASS; i += 256) W2s[i] = W2[i];
  __syncthreads();
  int row = blockIdx.x * 256 + threadIdx.x;
  if (row >= M) return;
  const float4* W2v = (const float4*)W2s;
  float4 acc[10];
#pragma unroll
  for (int j = 0; j < 10; ++j) acc[j] = make_float4(0.f, 0.f, 0.f, 0.f);
  const uint4* hp = (const uint4*)(H + (size_t)row * NHID);
  for (int kb = 0; kb < 32; ++kb) {
    uint4 u = hp[kb];
    float a[8] = {bflo(u.x), bfhi(u.x), bflo(u.y), bfhi(u.y),
                  bflo(u.z), bfhi(u.z), bflo(u.w), bfhi(u.w)};
#pragma unroll
    for (int kk = 0; kk < 8; ++kk) {
#pragma unroll
      for (int j = 0; j < 10; ++j) {
        float4 wv = W2v[(kb * 8 + kk) * 10 + j];
        acc[j].x += a[kk] * wv.x;
        acc[j].y += a[kk] * wv.y;
        acc[j].z += a[kk] * wv.z;
        acc[j].w += a[kk] * wv.w;
      }
    }
  }
  uint2* outp = (uint2*)(S2 + (size_t)row * NCLASS);
#pragma unroll
  for (int j = 0; j < 10; j += 2) {
    uint2 o0, o1;
    o0.x = (unsigned)f2bf(acc[j].x) | ((unsigned)f2bf(acc[j].y) << 16);
    o0.y = (unsigned)f2bf(acc[j].z) | ((unsigned)f2bf(acc[j].w) << 16);
    o1.x = (unsigned)f2bf(acc[j + 1].x) | ((unsigned)f2bf(acc[j + 1].y) << 16);
    o1.y = (unsigned)f2bf(acc[j + 1].z) | ((unsigned)f2bf(acc[j + 1].w) << 16);
    outp[j] = o0;
    outp[j + 1] = o1;
  }
}

// -------- SpMM2 (CSR, bf16) + bias + log_softmax, one wave per node -------
__global__ __launch_bounds__(256) void spmm2_csr_kernel(
    const ushort* __restrict__ S2, const int* __restrict__ rowptr,
    const int* __restrict__ deg, const int2* __restrict__ ep,
    const float* __restrict__ b2, float* __restrict__ out, int M) {
  int wid = (blockIdx.x * 256 + threadIdx.x) >> 6;
  int lane = threadIdx.x & 63;
  if (wid >= M) return;
  int beg = rowptr[wid];
  int n = deg[wid];
  float acc0 = 0.f, acc1 = 0.f;
  const ushort* S2l = S2 + lane * 2;
  for (int j0 = 0; j0 < n; j0 += 64) {
    int cnt = min(64, n - j0);
    int msrc = 0;
    float mw = 0.f;
    if (lane < cnt) {
      int2 e = ep[beg + j0 + lane];
      msrc = e.x;
      mw = __int_as_float(e.y);
    }
    for (int j = 0; j < cnt; ++j) {
      int s = __shfl(msrc, j);
      float wt = __shfl(mw, j);
      if (lane < 20) {
        unsigned u = *(const unsigned*)(S2l + (size_t)s * NCLASS);
        acc0 += wt * bflo(u);
        acc1 += wt * bfhi(u);
      }
    }
  }
  float v0 = -INFINITY, v1 = -INFINITY;
  if (lane < 20) {
    float2 b = *(const float2*)(b2 + lane * 2);
    v0 = acc0 + b.x;
    v1 = acc1 + b.y;
  }
  float m = fmaxf(v0, v1);
#pragma unroll
  for (int off = 32; off; off >>= 1) m = fmaxf(m, __shfl_xor(m, off));
  float ex = (lane < 20) ? __expf(v0 - m) + __expf(v1 - m) : 0.f;
  float s = ex;
#pragma unroll
  for (int off = 32; off; off >>= 1) s += __shfl_xor(s, off);
  float lse = m + __logf(s);
  if (lane < 20) {
    float2 o = {v0 - lse, v1 - lse};
    *(float2*)(out + (size_t)wid * NCLASS + lane * 2) = o;
  }
}

// ---------------------------------------------------------------------------
extern "C" void kernel_launch(void* const* d_in, const int* in_sizes, int n_in,
                              void* d_out, int out_size, void* d_ws,
                              size_t ws_size, hipStream_t stream) {
  const float* x  = (const float*)d_in[0];
  const int* esrc = (const int*)d_in[1];
  const int* edst = (const int*)d_in[2];
  const float* ew = (const float*)d_in[3];
  const float* W1 = (const float*)d_in[4];
  const float* b1 = (const float*)d_in[5];
  const float* W2 = (const float*)d_in[6];
  const float* b2 = (const float*)d_in[7];
  float* out = (float*)d_out;

  const int M = in_sizes[0] / NFEAT;  // 100000
  const int E = in_sizes[1];          // 3200000
  const int nbkt = (M + BKT_NODES - 1) / BKT_NODES;  // 196

  char* p = (char*)d_ws;
  ushort* support1 = (ushort*)p;           p += (size_t)M * NHID * 2;
  ushort* h        = (ushort*)p;           p += (size_t)M * NHID * 2;
  ushort* support2 = (ushort*)p;           p += (size_t)M * NCLASS * 2;
  ushort* W1t      = (ushort*)p;           p += (size_t)NFEAT * NHID * 2;
  int*    deg      = (int*)p;              p += (size_t)M * 4;
  int*    part     = (int*)p;              p += (size_t)M * 4;
  int*    rowptr   = (int*)p;              p += (size_t)M * 4;
  int*    gcursor  = (int*)p;              p += MAX_BKT * 4;
  int*    bsums    = (int*)p;              p += 512 * 4;
  int2*   ep       = (int2*)p;             p += (size_t)E * 8;
  int2*   tmp_sw   = (int2*)p;             p += (size_t)E * 8;
  ushort* tmp_d    = (ushort*)p;           // E * 2

  const int nbScan = (M + 255) / 256;  // 391 <= 512

  // ---- CSR build: hist -> rowptr -> bucketed counting sort ----
  hipMemsetAsync(deg, 0, (size_t)M * sizeof(int), stream);
  hist_kernel<<<(E + 255) / 256, 256, 0, stream>>>(edst, deg, E);
  scan1_kernel<<<nbScan, 256, 0, stream>>>(deg, part, bsums, M);
  scan2_kernel<<<1, 512, 0, stream>>>(bsums, nbScan);
  scan3_kernel<<<nbScan, 256, 0, stream>>>(part, bsums, deg, rowptr, M);
  initcur_kernel<<<1, 256, 0, stream>>>(rowptr, gcursor, nbkt);
  binA_kernel<<<(E + BIN_EPB - 1) / BIN_EPB, 256, 0, stream>>>(
      esrc, edst, ew, gcursor, tmp_sw, tmp_d, E);
  binB_kernel<<<nbkt, 512, 0, stream>>>(tmp_sw, tmp_d, rowptr, ep, M, E);

  // ---- layer 1 ----
  w1t_kernel<<<(NFEAT * NHID) / 256, 256, 0, stream>>>(W1, W1t);
  dim3 g1(NHID / 128, (M + 127) / 128);
  gemm1_mfma<<<g1, 256, 0, stream>>>(x, W1t, support1, M);
  spmm1_csr_kernel<<<(M * 64 + 255) / 256, 256, 0, stream>>>(
      support1, rowptr, deg, ep, b1, h, M);

  // ---- layer 2 ----
  gemm2_kernel<<<(M + 255) / 256, 256, 0, stream>>>(h, W2, support2, M);
  spmm2_csr_kernel<<<(M * 64 + 255) / 256, 256, 0, stream>>>(
      support2, rowptr, deg, ep, b2, out, M);
}